// Round 1
// baseline (551.456 us; speedup 1.0000x reference)
//
#include <hip/hip_runtime.h>
#include <cstdint>
#include <cstddef>

// N=4, L=2048, E=1024, H=16, D=64.  Token rows M = N*L = 8192.  HD = E = 1024.
// Pipeline: cvt fp32->bf16, 3 proj GEMMs (V transposed via operand swap),
// flash attention (online softmax, log2 domain), output GEMM (fp32 out).

typedef __bf16 bf16x8 __attribute__((ext_vector_type(8)));
typedef float f32x4 __attribute__((ext_vector_type(4)));

#define LOG2E_OVER_SQRTD 0.18033688011112042f  // log2(e)/8, folded into q

__device__ __forceinline__ unsigned short f2bf(float f) {
  unsigned int u = __builtin_bit_cast(unsigned int, f);
  u = (u + 0x7fffu + ((u >> 16) & 1u)) >> 16;  // RNE
  return (unsigned short)u;
}

// async 16B global->LDS (m97's width-16 global_load_lds)
__device__ __forceinline__ void gl2lds16(const void* g, void* l) {
  __builtin_amdgcn_global_load_lds(
      (__attribute__((address_space(1))) unsigned int*)g,
      (__attribute__((address_space(3))) unsigned int*)l, 16, 0, 0);
}

// ---------------------------------------------------------------- cvt kernel
__global__ __launch_bounds__(256) void cvt_f32_bf16_k(
    const float* __restrict__ src, unsigned short* __restrict__ dst) {
  size_t i = ((size_t)blockIdx.x * 256 + threadIdx.x) * 4;
  float4 v = *(const float4*)(src + i);
  ushort4 o;
  o.x = f2bf(v.x); o.y = f2bf(v.y); o.z = f2bf(v.z); o.w = f2bf(v.w);
  *(ushort4*)(dst + i) = o;
}

// ---------------------------------------------------------------- GEMM
// C[M][N] = A[M][K=1024] @ Bt[N][K=1024]^T, bf16 in, fp32 acc.
// 128x128 block tile, BK=32, 4 waves each 64x64 (4x4 of 16x16x32 MFMA).
// LDS XOR-swizzle: seg' = seg ^ ((row>>1)&3) -> conflict-free-ish ds_read_b128.
template <bool OUT_F32, bool BIAS_ROW>
__global__ __launch_bounds__(256, 2) void gemm_bt_k(
    const unsigned short* __restrict__ A, const unsigned short* __restrict__ Bt,
    const float* __restrict__ bias, void* __restrict__ Cv, int M, int N,
    float out_scale) {
  __shared__ __attribute__((aligned(16))) unsigned short As[128 * 32];
  __shared__ __attribute__((aligned(16))) unsigned short Bs[128 * 32];
  const int tid = threadIdx.x;
  const int lane = tid & 63, wave = tid >> 6;
  const int lr = lane & 15, lg = lane >> 4;
  const int rowBase = blockIdx.y * 128;
  const int colBase = blockIdx.x * 128;
  const int wm = (wave & 1) * 64, wn = (wave >> 1) * 64;

  f32x4 acc[4][4] = {};

  // two staging slots per thread per matrix: slot s -> row=s>>2, seg t=s&3,
  // fetch global seg c = t ^ ((row>>1)&3) so reader's swizzle finds it.
  const int s0 = tid, s1 = tid + 256;
  const int r0 = s0 >> 2, c0 = (s0 & 3) ^ ((r0 >> 1) & 3);
  const int r1 = s1 >> 2, c1 = (s1 & 3) ^ ((r1 >> 1) & 3);
  const unsigned short* gA0 = A + (size_t)(rowBase + r0) * 1024 + c0 * 8;
  const unsigned short* gA1 = A + (size_t)(rowBase + r1) * 1024 + c1 * 8;
  const unsigned short* gB0 = Bt + (size_t)(colBase + r0) * 1024 + c0 * 8;
  const unsigned short* gB1 = Bt + (size_t)(colBase + r1) * 1024 + c1 * 8;
  unsigned short* lA0 = &As[s0 * 8];
  unsigned short* lA1 = &As[s1 * 8];
  unsigned short* lB0 = &Bs[s0 * 8];
  unsigned short* lB1 = &Bs[s1 * 8];

  for (int kt = 0; kt < 32; ++kt) {
    gl2lds16(gA0 + kt * 32, lA0);
    gl2lds16(gA1 + kt * 32, lA1);
    gl2lds16(gB0 + kt * 32, lB0);
    gl2lds16(gB1 + kt * 32, lB1);
    __syncthreads();  // drains vmcnt before barrier (m97 structure)

    bf16x8 af[4], bfr[4];
#pragma unroll
    for (int mt = 0; mt < 4; ++mt) {
      int row = wm + mt * 16 + lr;
      int seg = lg ^ ((row >> 1) & 3);
      af[mt] = *(const bf16x8*)&As[row * 32 + seg * 8];
    }
#pragma unroll
    for (int nt = 0; nt < 4; ++nt) {
      int row = wn + nt * 16 + lr;
      int seg = lg ^ ((row >> 1) & 3);
      bfr[nt] = *(const bf16x8*)&Bs[row * 32 + seg * 8];
    }
#pragma unroll
    for (int mt = 0; mt < 4; ++mt)
#pragma unroll
      for (int nt = 0; nt < 4; ++nt)
        acc[mt][nt] = __builtin_amdgcn_mfma_f32_16x16x32_bf16(
            af[mt], bfr[nt], acc[mt][nt], 0, 0, 0);
    __syncthreads();  // waves done reading before restage
  }

  // epilogue: C-layout col=lane&15, row=(lane>>4)*4+reg  (m89/m91-verified)
#pragma unroll
  for (int mt = 0; mt < 4; ++mt)
#pragma unroll
    for (int nt = 0; nt < 4; ++nt) {
      int col = colBase + wn + nt * 16 + lr;
      float bcol = BIAS_ROW ? 0.f : bias[col];
#pragma unroll
      for (int r = 0; r < 4; ++r) {
        int row = rowBase + wm + mt * 16 + lg * 4 + r;
        float b = BIAS_ROW ? bias[row] : bcol;
        float val = (acc[mt][nt][r] + b) * out_scale;
        size_t idx = (size_t)row * (size_t)N + (size_t)col;
        if (OUT_F32)
          ((float*)Cv)[idx] = val;
        else
          ((unsigned short*)Cv)[idx] = f2bf(val);
      }
    }
}

// ---------------------------------------------------------------- attention
// One block per (n, h, 128-row q-tile).  4 waves x 32 q-rows.
// qb pre-scaled by log2(e)/sqrt(D) -> exp2 is native v_exp_f32.
__global__ __launch_bounds__(256) void attn_k(
    const unsigned short* __restrict__ qb,   // [8192][1024]
    const unsigned short* __restrict__ kb,   // [8192][1024]
    const unsigned short* __restrict__ vtb,  // [1024][8192]  (row = h*64+d)
    unsigned short* __restrict__ aob) {      // [8192][1024]
  __shared__ __attribute__((aligned(16))) unsigned short Qs[128 * 64];
  __shared__ __attribute__((aligned(16))) unsigned short Ks[64 * 64];
  __shared__ __attribute__((aligned(16))) unsigned short Vts[64 * 64];
  __shared__ __attribute__((aligned(16))) unsigned short Ps[4][32 * 72];  // +pad

  const int tid = threadIdx.x;
  const int lane = tid & 63, wave = tid >> 6;
  const int lr = lane & 15, lg = lane >> 4;

  const int bid = blockIdx.x;
  const int qt = bid & 15;       // 16 q-tiles of 128
  const int nh = bid >> 4;       // 0..63
  const int h = nh & 15, n = nh >> 4;
  const int q0 = qt * 128;

  // stage Q tile (128 rows x 64 d), XOR-swizzled by (row&7)
#pragma unroll
  for (int i = 0; i < 4; ++i) {
    int s = i * 256 + tid;
    int row = s >> 3;
    int c = (s & 7) ^ (row & 7);
    gl2lds16(qb + (((size_t)n * 2048 + q0 + row) << 10) + h * 64 + c * 8,
             &Qs[s * 8]);
  }

  f32x4 o_acc[2][4] = {};
  float mrow[2][4], lrow[2][4];
#pragma unroll
  for (int mt = 0; mt < 2; ++mt)
#pragma unroll
    for (int r = 0; r < 4; ++r) {
      mrow[mt][r] = -1e30f;
      lrow[mt][r] = 0.f;
    }

  for (int kt = 0; kt < 32; ++kt) {
    const int k0 = kt * 64;
#pragma unroll
    for (int i = 0; i < 2; ++i) {
      int s = i * 256 + tid;
      int row = s >> 3;
      int c = (s & 7) ^ (row & 7);
      gl2lds16(kb + (((size_t)n * 2048 + k0 + row) << 10) + h * 64 + c * 8,
               &Ks[s * 8]);
      gl2lds16(vtb + (((size_t)(h * 64 + row)) << 13) + (size_t)n * 2048 + k0 +
                   c * 8,
               &Vts[s * 8]);
    }
    __syncthreads();

    // S = Q K^T  (pre-scaled)
    f32x4 s_acc[2][4] = {};
    bf16x8 aq[2][2];
#pragma unroll
    for (int mt = 0; mt < 2; ++mt)
#pragma unroll
      for (int ks = 0; ks < 2; ++ks) {
        int row = wave * 32 + mt * 16 + lr;
        int cseg = (ks * 4 + lg) ^ (row & 7);
        aq[mt][ks] = *(const bf16x8*)&Qs[row * 64 + cseg * 8];
      }
#pragma unroll
    for (int ks = 0; ks < 2; ++ks)
#pragma unroll
      for (int nt = 0; nt < 4; ++nt) {
        int row = nt * 16 + lr;
        int cseg = (ks * 4 + lg) ^ (row & 7);
        bf16x8 bk = *(const bf16x8*)&Ks[row * 64 + cseg * 8];
#pragma unroll
        for (int mt = 0; mt < 2; ++mt)
          s_acc[mt][nt] = __builtin_amdgcn_mfma_f32_16x16x32_bf16(
              aq[mt][ks], bk, s_acc[mt][nt], 0, 0, 0);
      }

    // online softmax (log2 domain); row = lg*4+r lives in this lane's quad,
    // its 16 cols in lanes of the same quad -> shfl_xor 1/2/4/8.
#pragma unroll
    for (int mt = 0; mt < 2; ++mt)
#pragma unroll
      for (int r = 0; r < 4; ++r) {
        float v = fmaxf(fmaxf(s_acc[mt][0][r], s_acc[mt][1][r]),
                        fmaxf(s_acc[mt][2][r], s_acc[mt][3][r]));
        v = fmaxf(v, __shfl_xor(v, 1));
        v = fmaxf(v, __shfl_xor(v, 2));
        v = fmaxf(v, __shfl_xor(v, 4));
        v = fmaxf(v, __shfl_xor(v, 8));
        float mold = mrow[mt][r];
        float mnew = fmaxf(mold, v);
        float alpha = __builtin_exp2f(mold - mnew);
        mrow[mt][r] = mnew;
        float psum = 0.f;
#pragma unroll
        for (int nt = 0; nt < 4; ++nt) {
          float p = __builtin_exp2f(s_acc[mt][nt][r] - mnew);
          s_acc[mt][nt][r] = p;
          psum += p;
        }
        psum += __shfl_xor(psum, 1);
        psum += __shfl_xor(psum, 2);
        psum += __shfl_xor(psum, 4);
        psum += __shfl_xor(psum, 8);
        lrow[mt][r] = lrow[mt][r] * alpha + psum;
#pragma unroll
        for (int nt = 0; nt < 4; ++nt) o_acc[mt][nt][r] *= alpha;
        int prow = mt * 16 + lg * 4 + r;
#pragma unroll
        for (int nt = 0; nt < 4; ++nt)
          Ps[wave][prow * 72 + nt * 16 + lr] = f2bf(s_acc[mt][nt][r]);
      }

    // O += P V   (P read back in A-layout from wave-private LDS; in-wave
    // RAW on same LDS array -> compiler inserts lgkmcnt wait, no barrier)
#pragma unroll
    for (int ks = 0; ks < 2; ++ks) {
      bf16x8 ap[2], bv[4];
#pragma unroll
      for (int mt = 0; mt < 2; ++mt)
        ap[mt] = *(const bf16x8*)&Ps[wave][(mt * 16 + lr) * 72 + ks * 32 +
                                           lg * 8];
#pragma unroll
      for (int nt = 0; nt < 4; ++nt) {
        int row = nt * 16 + lr;
        int cseg = (ks * 4 + lg) ^ (row & 7);
        bv[nt] = *(const bf16x8*)&Vts[row * 64 + cseg * 8];
      }
#pragma unroll
      for (int mt = 0; mt < 2; ++mt)
#pragma unroll
        for (int nt = 0; nt < 4; ++nt)
          o_acc[mt][nt] = __builtin_amdgcn_mfma_f32_16x16x32_bf16(
              ap[mt], bv[nt], o_acc[mt][nt], 0, 0, 0);
    }
    __syncthreads();  // all waves done with Ks/Vts before restage
  }

#pragma unroll
  for (int mt = 0; mt < 2; ++mt)
#pragma unroll
    for (int r = 0; r < 4; ++r) {
      float inv = 1.0f / lrow[mt][r];
      int row_l = q0 + wave * 32 + mt * 16 + lg * 4 + r;
      size_t base = (((size_t)n * 2048 + row_l) << 10) + h * 64;
#pragma unroll
      for (int nt = 0; nt < 4; ++nt)
        aob[base + nt * 16 + lr] = f2bf(o_acc[mt][nt][r] * inv);
    }
}

// ---------------------------------------------------------------- launch
extern "C" void kernel_launch(void* const* d_in, const int* in_sizes, int n_in,
                              void* d_out, int out_size, void* d_ws,
                              size_t ws_size, hipStream_t stream) {
  const float* Q = (const float*)d_in[0];
  const float* K = (const float*)d_in[1];
  const float* V = (const float*)d_in[2];
  const float* Wq = (const float*)d_in[3];
  const float* bq = (const float*)d_in[4];
  const float* Wk = (const float*)d_in[5];
  const float* bk = (const float*)d_in[6];
  const float* Wv = (const float*)d_in[7];
  const float* bv = (const float*)d_in[8];
  const float* Wo = (const float*)d_in[9];
  const float* bo = (const float*)d_in[10];

  const size_t S = (size_t)8192 * 1024;
  const size_t W = (size_t)1024 * 1024;
  unsigned short* ws = (unsigned short*)d_ws;
  unsigned short* Qbf = ws;  // dead after q-proj; reused as attention output
  unsigned short* Kbf = ws + S;
  unsigned short* Vbf = ws + 2 * S;
  unsigned short* qbuf = ws + 3 * S;
  unsigned short* kbuf = ws + 4 * S;
  unsigned short* vtbuf = ws + 5 * S;
  unsigned short* Wqb = ws + 6 * S;
  unsigned short* Wkb = Wqb + W;
  unsigned short* Wvb = Wqb + 2 * W;
  unsigned short* Wob = Wqb + 3 * W;
  unsigned short* aob = Qbf;
  // total ws use: 6*S + 4*W bf16 = ~109 MB

  cvt_f32_bf16_k<<<8192, 256, 0, stream>>>(Q, Qbf);
  cvt_f32_bf16_k<<<8192, 256, 0, stream>>>(K, Kbf);
  cvt_f32_bf16_k<<<8192, 256, 0, stream>>>(V, Vbf);
  cvt_f32_bf16_k<<<1024, 256, 0, stream>>>(Wq, Wqb);
  cvt_f32_bf16_k<<<1024, 256, 0, stream>>>(Wk, Wkb);
  cvt_f32_bf16_k<<<1024, 256, 0, stream>>>(Wv, Wvb);
  cvt_f32_bf16_k<<<1024, 256, 0, stream>>>(Wo, Wob);

  // q = (X Wq^T + bq) * log2(e)/8 ;  k = X Wk^T + bk
  gemm_bt_k<false, false><<<dim3(8, 64), 256, 0, stream>>>(
      Qbf, Wqb, bq, qbuf, 8192, 1024, LOG2E_OVER_SQRTD);
  gemm_bt_k<false, false><<<dim3(8, 64), 256, 0, stream>>>(
      Kbf, Wkb, bk, kbuf, 8192, 1024, 1.0f);
  // v^T = Wv X^T + bv  (operand swap -> transposed layout for free)
  gemm_bt_k<false, true><<<dim3(64, 8), 256, 0, stream>>>(
      Wvb, Vbf, bv, vtbuf, 1024, 8192, 1.0f);

  attn_k<<<1024, 256, 0, stream>>>(qbuf, kbuf, vtbuf, aob);

  // out = AO Wo^T + bo  (fp32)
  gemm_bt_k<true, false><<<dim3(8, 64), 256, 0, stream>>>(
      aob, Wob, bo, d_out, 8192, 1024, 1.0f);
}

// Round 2
// 353.529 us; speedup vs baseline: 1.5599x; 1.5599x over previous
//
#include <hip/hip_runtime.h>
#include <cstdint>
#include <cstddef>

// N=4, L=2048, E=1024, H=16, D=64.  Token rows M = N*L = 8192.
// Pipeline: cvt fp32->bf16 (2 fused launches), 3 proj GEMMs (V transposed AND
// key-permuted via epilogue), no-max flash attention (exp2 log2-domain,
// deferred row-sum), output GEMM (fp32 out).

typedef __bf16 bf16x8 __attribute__((ext_vector_type(8)));
typedef __bf16 bf16x4 __attribute__((ext_vector_type(4)));
typedef float f32x4 __attribute__((ext_vector_type(4)));

#define LOG2E_OVER_SQRTD 0.18033688011112042f  // log2(e)/8, folded into q

__device__ __forceinline__ unsigned short f2bf(float f) {
  unsigned int u = __builtin_bit_cast(unsigned int, f);
  u = (u + 0x7fffu + ((u >> 16) & 1u)) >> 16;  // RNE
  return (unsigned short)u;
}

// async 16B global->LDS
__device__ __forceinline__ void gl2lds16(const void* g, void* l) {
  __builtin_amdgcn_global_load_lds(
      (__attribute__((address_space(1))) unsigned int*)g,
      (__attribute__((address_space(3))) unsigned int*)l, 16, 0, 0);
}

// ---------------------------------------------------------------- cvt kernel
struct CvtArgs {
  const float* src[4];
  unsigned short* dst[4];
};
__global__ __launch_bounds__(256) void cvt_multi_k(CvtArgs a) {
  const float* s = a.src[blockIdx.y];
  unsigned short* d = a.dst[blockIdx.y];
  size_t i = ((size_t)blockIdx.x * 256 + threadIdx.x) * 4;
  float4 v = *(const float4*)(s + i);
  ushort4 o;
  o.x = f2bf(v.x); o.y = f2bf(v.y); o.z = f2bf(v.z); o.w = f2bf(v.w);
  *(ushort4*)(d + i) = o;
}

// ---------------------------------------------------------------- GEMM
// C[M][N] = A[M][K=1024] @ Bt[N][K=1024]^T, bf16 in, fp32 acc.
// 128x128 tile, BK=32, 4 waves each 64x64.  PERMC: store cols permuted
// within each 64-group: col' = (col&~63) | (4*(col&15) + ((col>>4)&3)).
template <bool OUT_F32, bool BIAS_ROW, bool PERMC>
__global__ __launch_bounds__(256, 2) void gemm_bt_k(
    const unsigned short* __restrict__ A, const unsigned short* __restrict__ Bt,
    const float* __restrict__ bias, void* __restrict__ Cv, int M, int N,
    float out_scale) {
  __shared__ __attribute__((aligned(16))) unsigned short As[128 * 32];
  __shared__ __attribute__((aligned(16))) unsigned short Bs[128 * 32];
  const int tid = threadIdx.x;
  const int lane = tid & 63, wave = tid >> 6;
  const int lr = lane & 15, lg = lane >> 4;
  const int rowBase = blockIdx.y * 128;
  const int colBase = blockIdx.x * 128;
  const int wm = (wave & 1) * 64, wn = (wave >> 1) * 64;

  f32x4 acc[4][4] = {};

  const int s0 = tid, s1 = tid + 256;
  const int r0 = s0 >> 2, c0 = (s0 & 3) ^ ((r0 >> 1) & 3);
  const int r1 = s1 >> 2, c1 = (s1 & 3) ^ ((r1 >> 1) & 3);
  const unsigned short* gA0 = A + (size_t)(rowBase + r0) * 1024 + c0 * 8;
  const unsigned short* gA1 = A + (size_t)(rowBase + r1) * 1024 + c1 * 8;
  const unsigned short* gB0 = Bt + (size_t)(colBase + r0) * 1024 + c0 * 8;
  const unsigned short* gB1 = Bt + (size_t)(colBase + r1) * 1024 + c1 * 8;
  unsigned short* lA0 = &As[s0 * 8];
  unsigned short* lA1 = &As[s1 * 8];
  unsigned short* lB0 = &Bs[s0 * 8];
  unsigned short* lB1 = &Bs[s1 * 8];

  for (int kt = 0; kt < 32; ++kt) {
    gl2lds16(gA0 + kt * 32, lA0);
    gl2lds16(gA1 + kt * 32, lA1);
    gl2lds16(gB0 + kt * 32, lB0);
    gl2lds16(gB1 + kt * 32, lB1);
    __syncthreads();

    bf16x8 af[4], bfr[4];
#pragma unroll
    for (int mt = 0; mt < 4; ++mt) {
      int row = wm + mt * 16 + lr;
      int seg = lg ^ ((row >> 1) & 3);
      af[mt] = *(const bf16x8*)&As[row * 32 + seg * 8];
    }
#pragma unroll
    for (int nt = 0; nt < 4; ++nt) {
      int row = wn + nt * 16 + lr;
      int seg = lg ^ ((row >> 1) & 3);
      bfr[nt] = *(const bf16x8*)&Bs[row * 32 + seg * 8];
    }
#pragma unroll
    for (int mt = 0; mt < 4; ++mt)
#pragma unroll
      for (int nt = 0; nt < 4; ++nt)
        acc[mt][nt] = __builtin_amdgcn_mfma_f32_16x16x32_bf16(
            af[mt], bfr[nt], acc[mt][nt], 0, 0, 0);
    __syncthreads();
  }

  // epilogue: C-layout col=lane&15, row=(lane>>4)*4+reg
#pragma unroll
  for (int mt = 0; mt < 4; ++mt)
#pragma unroll
    for (int nt = 0; nt < 4; ++nt) {
      int col = colBase + wn + nt * 16 + lr;
      int colStore = PERMC ? (colBase + wn + lr * 4 + nt) : col;
      float bcol = BIAS_ROW ? 0.f : bias[col];
#pragma unroll
      for (int r = 0; r < 4; ++r) {
        int row = rowBase + wm + mt * 16 + lg * 4 + r;
        float b = BIAS_ROW ? bias[row] : bcol;
        float val = (acc[mt][nt][r] + b) * out_scale;
        size_t idx = (size_t)row * (size_t)N + (size_t)colStore;
        if (OUT_F32)
          ((float*)Cv)[idx] = val;
        else
          ((unsigned short*)Cv)[idx] = f2bf(val);
      }
    }
}

// ---------------------------------------------------------------- attention
// One block per (n, h, 128-row q-tile).  4 waves x 32 q-rows.  KT=64.
// qb pre-scaled by log2(e)/sqrt(D); no-max softmax: p=exp2(s) directly,
// row-sum deferred to epilogue (per-lane partials).  V is key-permuted
// (k'=4*(k&15)+(k>>4) per 64-group) so P-writes are contiguous b64.
__global__ __launch_bounds__(256, 4) void attn_k(
    const unsigned short* __restrict__ qb,   // [8192][1024]
    const unsigned short* __restrict__ kb,   // [8192][1024]
    const unsigned short* __restrict__ vtb,  // [1024][8192] key-permuted
    unsigned short* __restrict__ aob) {      // [8192][1024]
  __shared__ __attribute__((aligned(16))) unsigned short Ks[64 * 64];
  __shared__ __attribute__((aligned(16))) unsigned short Vts[64 * 64];
  // first used to stage the 128x64 Q tile (8192 shorts), then 4 wave-private
  // 32x72 P buffers
  __shared__ __attribute__((aligned(16))) unsigned short QPs[4 * 32 * 72];

  const int tid = threadIdx.x;
  const int lane = tid & 63, wave = tid >> 6;
  const int lr = lane & 15, lg = lane >> 4;

  const int bid = blockIdx.x;
  const int qt = bid & 15;
  const int nh = bid >> 4;
  const int h = nh & 15, n = nh >> 4;
  const int q0 = qt * 128;

  // stage Q tile (chunk swizzle c^(row&7)) + K/V for kt=0
#pragma unroll
  for (int i = 0; i < 4; ++i) {
    int s = i * 256 + tid;
    int row = s >> 3;
    int c = (s & 7) ^ (row & 7);
    gl2lds16(qb + (((size_t)n * 2048 + q0 + row) << 10) + h * 64 + c * 8,
             &QPs[s * 8]);
  }
#pragma unroll
  for (int i = 0; i < 2; ++i) {
    int s = i * 256 + tid;
    int row = s >> 3;
    int c = (s & 7) ^ (row & 7);
    gl2lds16(kb + (((size_t)n * 2048 + row) << 10) + h * 64 + c * 8, &Ks[s * 8]);
    gl2lds16(vtb + (((size_t)(h * 64 + row)) << 13) + (size_t)n * 2048 + c * 8,
             &Vts[s * 8]);
  }
  __syncthreads();

  // hoist Q fragments (loop-invariant)
  bf16x8 aq[2][2];
#pragma unroll
  for (int mt = 0; mt < 2; ++mt)
#pragma unroll
    for (int ks = 0; ks < 2; ++ks) {
      int row = wave * 32 + mt * 16 + lr;
      int c = (ks * 4 + lg) ^ (row & 7);
      aq[mt][ks] = *(const bf16x8*)&QPs[row * 64 + c * 8];
    }
  __syncthreads();  // all Q reads done; QPs becomes P space

  unsigned short* PsW = &QPs[wave * (32 * 72)];

  f32x4 o_acc[2][4] = {};
  float lrow[2][4] = {};

  for (int kt = 0; kt < 32; ++kt) {
    // S = Q K^T (pre-scaled to log2 domain)
    f32x4 s_acc[2][4] = {};
#pragma unroll
    for (int ks = 0; ks < 2; ++ks)
#pragma unroll
      for (int nt = 0; nt < 4; ++nt) {
        int row = nt * 16 + lr;
        int c = (ks * 4 + lg) ^ (row & 7);
        bf16x8 bk = *(const bf16x8*)&Ks[row * 64 + c * 8];
#pragma unroll
        for (int mt = 0; mt < 2; ++mt)
          s_acc[mt][nt] = __builtin_amdgcn_mfma_f32_16x16x32_bf16(
              aq[mt][ks], bk, s_acc[mt][nt], 0, 0, 0);
      }

    // p = exp2(s); accumulate row-sum partials; write P (b64, permuted cols)
#pragma unroll
    for (int mt = 0; mt < 2; ++mt) {
      f32x4 p[4];
#pragma unroll
      for (int nt = 0; nt < 4; ++nt)
#pragma unroll
        for (int r = 0; r < 4; ++r)
          p[nt][r] = __builtin_amdgcn_exp2f(s_acc[mt][nt][r]);
#pragma unroll
      for (int r = 0; r < 4; ++r) {
        lrow[mt][r] += (p[0][r] + p[1][r]) + (p[2][r] + p[3][r]);
        f32x4 v4 = {p[0][r], p[1][r], p[2][r], p[3][r]};
        bf16x4 pk = __builtin_convertvector(v4, bf16x4);
        int prow = mt * 16 + lg * 4 + r;
        *(bf16x4*)&PsW[prow * 72 + lr * 4] = pk;
      }
    }

    // O += P V' (k' permuted consistently in P and V)
#pragma unroll
    for (int ks = 0; ks < 2; ++ks) {
      bf16x8 ap[2], bv[4];
#pragma unroll
      for (int mt = 0; mt < 2; ++mt)
        ap[mt] = *(const bf16x8*)&PsW[(mt * 16 + lr) * 72 + ks * 32 + lg * 8];
#pragma unroll
      for (int nt = 0; nt < 4; ++nt) {
        int row = nt * 16 + lr;
        int c = (ks * 4 + lg) ^ (row & 7);
        bv[nt] = *(const bf16x8*)&Vts[row * 64 + c * 8];
      }
#pragma unroll
      for (int mt = 0; mt < 2; ++mt)
#pragma unroll
        for (int nt = 0; nt < 4; ++nt)
          o_acc[mt][nt] = __builtin_amdgcn_mfma_f32_16x16x32_bf16(
              ap[mt], bv[nt], o_acc[mt][nt], 0, 0, 0);
    }

    __syncthreads();  // all waves done reading Ks/Vts
    if (kt < 31) {
      const int k0 = (kt + 1) * 64;
#pragma unroll
      for (int i = 0; i < 2; ++i) {
        int s = i * 256 + tid;
        int row = s >> 3;
        int c = (s & 7) ^ (row & 7);
        gl2lds16(kb + (((size_t)n * 2048 + k0 + row) << 10) + h * 64 + c * 8,
                 &Ks[s * 8]);
        gl2lds16(vtb + (((size_t)(h * 64 + row)) << 13) + (size_t)n * 2048 +
                     k0 + c * 8,
                 &Vts[s * 8]);
      }
    }
    __syncthreads();  // drain staging before reads
  }

  // epilogue: one shfl-reduce for the row sums, normalize, store
#pragma unroll
  for (int mt = 0; mt < 2; ++mt)
#pragma unroll
    for (int r = 0; r < 4; ++r) {
      float l = lrow[mt][r];
      l += __shfl_xor(l, 1);
      l += __shfl_xor(l, 2);
      l += __shfl_xor(l, 4);
      l += __shfl_xor(l, 8);
      float inv = 1.0f / l;
      int row_l = q0 + wave * 32 + mt * 16 + lg * 4 + r;
      size_t base = (((size_t)n * 2048 + row_l) << 10) + h * 64;
#pragma unroll
      for (int nt = 0; nt < 4; ++nt)
        aob[base + nt * 16 + lr] = f2bf(o_acc[mt][nt][r] * inv);
    }
}

// ---------------------------------------------------------------- launch
extern "C" void kernel_launch(void* const* d_in, const int* in_sizes, int n_in,
                              void* d_out, int out_size, void* d_ws,
                              size_t ws_size, hipStream_t stream) {
  const float* Q = (const float*)d_in[0];
  const float* K = (const float*)d_in[1];
  const float* V = (const float*)d_in[2];
  const float* Wq = (const float*)d_in[3];
  const float* bq = (const float*)d_in[4];
  const float* Wk = (const float*)d_in[5];
  const float* bk = (const float*)d_in[6];
  const float* Wv = (const float*)d_in[7];
  const float* bv = (const float*)d_in[8];
  const float* Wo = (const float*)d_in[9];
  const float* bo = (const float*)d_in[10];

  const size_t S = (size_t)8192 * 1024;
  const size_t W = (size_t)1024 * 1024;
  unsigned short* ws = (unsigned short*)d_ws;
  unsigned short* Qbf = ws;  // dead after q-proj; reused as attention output
  unsigned short* Kbf = ws + S;
  unsigned short* Vbf = ws + 2 * S;
  unsigned short* qbuf = ws + 3 * S;
  unsigned short* kbuf = ws + 4 * S;
  unsigned short* vtbuf = ws + 5 * S;
  unsigned short* Wqb = ws + 6 * S;
  unsigned short* Wkb = Wqb + W;
  unsigned short* Wvb = Wqb + 2 * W;
  unsigned short* Wob = Wqb + 3 * W;
  unsigned short* aob = Qbf;

  CvtArgs cx;
  cx.src[0] = Q; cx.dst[0] = Qbf;
  cx.src[1] = K; cx.dst[1] = Kbf;
  cx.src[2] = V; cx.dst[2] = Vbf;
  cx.src[3] = Q; cx.dst[3] = Qbf;  // unused slot
  cvt_multi_k<<<dim3(8192, 3), 256, 0, stream>>>(cx);

  CvtArgs cw;
  cw.src[0] = Wq; cw.dst[0] = Wqb;
  cw.src[1] = Wk; cw.dst[1] = Wkb;
  cw.src[2] = Wv; cw.dst[2] = Wvb;
  cw.src[3] = Wo; cw.dst[3] = Wob;
  cvt_multi_k<<<dim3(1024, 4), 256, 0, stream>>>(cw);

  // q = (X Wq^T + bq) * log2(e)/8 ;  k = X Wk^T + bk
  gemm_bt_k<false, false, false><<<dim3(8, 64), 256, 0, stream>>>(
      Qbf, Wqb, bq, qbuf, 8192, 1024, LOG2E_OVER_SQRTD);
  gemm_bt_k<false, false, false><<<dim3(8, 64), 256, 0, stream>>>(
      Kbf, Wkb, bk, kbuf, 8192, 1024, 1.0f);
  // v^T = Wv X^T + bv, stored key-permuted per 64-group
  gemm_bt_k<false, true, true><<<dim3(64, 8), 256, 0, stream>>>(
      Wvb, Vbf, bv, vtbuf, 1024, 8192, 1.0f);

  attn_k<<<1024, 256, 0, stream>>>(qbuf, kbuf, vtbuf, aob);

  // out = AO Wo^T + bo  (fp32)
  gemm_bt_k<true, false, false><<<dim3(8, 64), 256, 0, stream>>>(
      aob, Wob, bo, d_out, 8192, 1024, 1.0f);
}

// Round 3
// 346.970 us; speedup vs baseline: 1.5893x; 1.0189x over previous
//
#include <hip/hip_runtime.h>
#include <cstdint>
#include <cstddef>

// N=4, L=2048, E=1024, H=16, D=64.  Token rows M = N*L = 8192.
// Pipeline: cvt fp32->bf16, fused QKV projection GEMM (one 1536-block
// launch, BK=64), no-max flash attention, output GEMM (fp32 out, BK=64).

typedef __bf16 bf16x8 __attribute__((ext_vector_type(8)));
typedef __bf16 bf16x4 __attribute__((ext_vector_type(4)));
typedef float f32x4 __attribute__((ext_vector_type(4)));

#define LOG2E_OVER_SQRTD 0.18033688011112042f  // log2(e)/8, folded into q

__device__ __forceinline__ unsigned short f2bf(float f) {
  unsigned int u = __builtin_bit_cast(unsigned int, f);
  u = (u + 0x7fffu + ((u >> 16) & 1u)) >> 16;  // RNE
  return (unsigned short)u;
}

// async 16B global->LDS
__device__ __forceinline__ void gl2lds16(const void* g, void* l) {
  __builtin_amdgcn_global_load_lds(
      (__attribute__((address_space(1))) unsigned int*)g,
      (__attribute__((address_space(3))) unsigned int*)l, 16, 0, 0);
}

// ---------------------------------------------------------------- cvt kernel
struct CvtArgs {
  const float* src[4];
  unsigned short* dst[4];
};
__global__ __launch_bounds__(256) void cvt_multi_k(CvtArgs a) {
  const float* s = a.src[blockIdx.y];
  unsigned short* d = a.dst[blockIdx.y];
  size_t i = ((size_t)blockIdx.x * 256 + threadIdx.x) * 4;
  float4 v = *(const float4*)(s + i);
  ushort4 o;
  o.x = f2bf(v.x); o.y = f2bf(v.y); o.z = f2bf(v.z); o.w = f2bf(v.w);
  *(ushort4*)(d + i) = o;
}

// ---------------------------------------------------------------- GEMM
// C[M][N] = A[M][1024] @ Bt[N][1024]^T, bf16 in, fp32 acc.  128x128 tile,
// BK=64 (16 K-iters), 4 waves each 64x64.  Multi-GEMM: blockIdx.x>>9 picks
// the descriptor (512 blocks per GEMM).
struct GemmDesc {
  const unsigned short* A;
  const unsigned short* Bt;
  const float* bias;
  void* C;
  int N;          // C column count / row stride
  int nbx_shift;  // log2(N/128)
  float scale;
  int bias_row;   // bias indexed by row instead of col
  int permc;      // store cols permuted: col' = 4*(col&15) + ((col>>4)&3)
};
struct GemmPack3 {
  GemmDesc g[3];
};

template <bool OUT_F32>
__global__ __launch_bounds__(256, 2) void gemm_multi_k(GemmPack3 p) {
  __shared__ __attribute__((aligned(16))) unsigned short As[128 * 64];
  __shared__ __attribute__((aligned(16))) unsigned short Bs[128 * 64];
  const GemmDesc d = p.g[blockIdx.x >> 9];
  const int t = blockIdx.x & 511;
  const int bx = t & ((1 << d.nbx_shift) - 1);
  const int by = t >> d.nbx_shift;

  const int tid = threadIdx.x;
  const int lane = tid & 63, wave = tid >> 6;
  const int lr = lane & 15, lg = lane >> 4;
  const int rowBase = by * 128;
  const int colBase = bx * 128;
  const int wm = (wave & 1) * 64, wn = (wave >> 1) * 64;

  f32x4 acc[4][4] = {};

  // staging: 4 slots/thread/matrix; slot s -> row=s>>3, seg t=s&7,
  // global chunk c = t ^ (row&7)  (reader swizzle matches)
  const unsigned short* gA[4];
  const unsigned short* gB[4];
  unsigned short* lA[4];
  unsigned short* lB[4];
#pragma unroll
  for (int i = 0; i < 4; ++i) {
    int s = tid + i * 256;
    int row = s >> 3;
    int c = (s & 7) ^ (row & 7);
    gA[i] = d.A + (size_t)(rowBase + row) * 1024 + c * 8;
    gB[i] = d.Bt + (size_t)(colBase + row) * 1024 + c * 8;
    lA[i] = &As[s * 8];
    lB[i] = &Bs[s * 8];
  }

  for (int kt = 0; kt < 16; ++kt) {
    const int ko = kt * 64;
#pragma unroll
    for (int i = 0; i < 4; ++i) {
      gl2lds16(gA[i] + ko, lA[i]);
      gl2lds16(gB[i] + ko, lB[i]);
    }
    __syncthreads();  // drains vmcnt before barrier (m97 structure)

#pragma unroll
    for (int ks = 0; ks < 2; ++ks) {
      bf16x8 af[4], bfr[4];
#pragma unroll
      for (int mt = 0; mt < 4; ++mt) {
        int row = wm + mt * 16 + lr;
        int c = (ks * 4 + lg) ^ (row & 7);
        af[mt] = *(const bf16x8*)&As[row * 64 + c * 8];
      }
#pragma unroll
      for (int nt = 0; nt < 4; ++nt) {
        int row = wn + nt * 16 + lr;
        int c = (ks * 4 + lg) ^ (row & 7);
        bfr[nt] = *(const bf16x8*)&Bs[row * 64 + c * 8];
      }
#pragma unroll
      for (int mt = 0; mt < 4; ++mt)
#pragma unroll
        for (int nt = 0; nt < 4; ++nt)
          acc[mt][nt] = __builtin_amdgcn_mfma_f32_16x16x32_bf16(
              af[mt], bfr[nt], acc[mt][nt], 0, 0, 0);
    }
    __syncthreads();  // waves done reading before restage
  }

  // epilogue: C-layout col=lane&15, row=(lane>>4)*4+reg
#pragma unroll
  for (int mt = 0; mt < 4; ++mt)
#pragma unroll
    for (int nt = 0; nt < 4; ++nt) {
      int col = colBase + wn + nt * 16 + lr;
      int colStore = d.permc ? (colBase + wn + lr * 4 + nt) : col;
      float bcol = d.bias_row ? 0.f : d.bias[col];
#pragma unroll
      for (int r = 0; r < 4; ++r) {
        int row = rowBase + wm + mt * 16 + lg * 4 + r;
        float b = d.bias_row ? d.bias[row] : bcol;
        float val = (acc[mt][nt][r] + b) * d.scale;
        size_t idx = (size_t)row * (size_t)d.N + (size_t)colStore;
        if (OUT_F32)
          ((float*)d.C)[idx] = val;
        else
          ((unsigned short*)d.C)[idx] = f2bf(val);
      }
    }
}

// ---------------------------------------------------------------- attention
// One block per (n, h, 128-row q-tile).  4 waves x 32 q-rows.  KT=64.
// qb pre-scaled by log2(e)/sqrt(D); no-max softmax: p=exp2(s) directly,
// row-sum deferred to epilogue.  V key-permuted so P-writes are b64.
__global__ __launch_bounds__(256, 4) void attn_k(
    const unsigned short* __restrict__ qb,   // [8192][1024]
    const unsigned short* __restrict__ kb,   // [8192][1024]
    const unsigned short* __restrict__ vtb,  // [1024][8192] key-permuted
    unsigned short* __restrict__ aob) {      // [8192][1024]
  __shared__ __attribute__((aligned(16))) unsigned short Ks[64 * 64];
  __shared__ __attribute__((aligned(16))) unsigned short Vts[64 * 64];
  __shared__ __attribute__((aligned(16))) unsigned short QPs[4 * 32 * 72];

  const int tid = threadIdx.x;
  const int lane = tid & 63, wave = tid >> 6;
  const int lr = lane & 15, lg = lane >> 4;

  const int bid = blockIdx.x;
  const int qt = bid & 15;
  const int nh = bid >> 4;
  const int h = nh & 15, n = nh >> 4;
  const int q0 = qt * 128;

#pragma unroll
  for (int i = 0; i < 4; ++i) {
    int s = i * 256 + tid;
    int row = s >> 3;
    int c = (s & 7) ^ (row & 7);
    gl2lds16(qb + (((size_t)n * 2048 + q0 + row) << 10) + h * 64 + c * 8,
             &QPs[s * 8]);
  }
#pragma unroll
  for (int i = 0; i < 2; ++i) {
    int s = i * 256 + tid;
    int row = s >> 3;
    int c = (s & 7) ^ (row & 7);
    gl2lds16(kb + (((size_t)n * 2048 + row) << 10) + h * 64 + c * 8, &Ks[s * 8]);
    gl2lds16(vtb + (((size_t)(h * 64 + row)) << 13) + (size_t)n * 2048 + c * 8,
             &Vts[s * 8]);
  }
  __syncthreads();

  bf16x8 aq[2][2];
#pragma unroll
  for (int mt = 0; mt < 2; ++mt)
#pragma unroll
    for (int ks = 0; ks < 2; ++ks) {
      int row = wave * 32 + mt * 16 + lr;
      int c = (ks * 4 + lg) ^ (row & 7);
      aq[mt][ks] = *(const bf16x8*)&QPs[row * 64 + c * 8];
    }
  __syncthreads();  // Q reads done; QPs becomes P space

  unsigned short* PsW = &QPs[wave * (32 * 72)];

  f32x4 o_acc[2][4] = {};
  float lrow[2][4] = {};

  for (int kt = 0; kt < 32; ++kt) {
    f32x4 s_acc[2][4] = {};
#pragma unroll
    for (int ks = 0; ks < 2; ++ks)
#pragma unroll
      for (int nt = 0; nt < 4; ++nt) {
        int row = nt * 16 + lr;
        int c = (ks * 4 + lg) ^ (row & 7);
        bf16x8 bk = *(const bf16x8*)&Ks[row * 64 + c * 8];
#pragma unroll
        for (int mt = 0; mt < 2; ++mt)
          s_acc[mt][nt] = __builtin_amdgcn_mfma_f32_16x16x32_bf16(
              aq[mt][ks], bk, s_acc[mt][nt], 0, 0, 0);
      }

#pragma unroll
    for (int mt = 0; mt < 2; ++mt) {
      f32x4 p[4];
#pragma unroll
      for (int nt = 0; nt < 4; ++nt)
#pragma unroll
        for (int r = 0; r < 4; ++r)
          p[nt][r] = __builtin_amdgcn_exp2f(s_acc[mt][nt][r]);
#pragma unroll
      for (int r = 0; r < 4; ++r) {
        lrow[mt][r] += (p[0][r] + p[1][r]) + (p[2][r] + p[3][r]);
        f32x4 v4 = {p[0][r], p[1][r], p[2][r], p[3][r]};
        bf16x4 pk = __builtin_convertvector(v4, bf16x4);
        int prow = mt * 16 + lg * 4 + r;
        *(bf16x4*)&PsW[prow * 72 + lr * 4] = pk;
      }
    }

#pragma unroll
    for (int ks = 0; ks < 2; ++ks) {
      bf16x8 ap[2], bv[4];
#pragma unroll
      for (int mt = 0; mt < 2; ++mt)
        ap[mt] = *(const bf16x8*)&PsW[(mt * 16 + lr) * 72 + ks * 32 + lg * 8];
#pragma unroll
      for (int nt = 0; nt < 4; ++nt) {
        int row = nt * 16 + lr;
        int c = (ks * 4 + lg) ^ (row & 7);
        bv[nt] = *(const bf16x8*)&Vts[row * 64 + c * 8];
      }
#pragma unroll
      for (int mt = 0; mt < 2; ++mt)
#pragma unroll
        for (int nt = 0; nt < 4; ++nt)
          o_acc[mt][nt] = __builtin_amdgcn_mfma_f32_16x16x32_bf16(
              ap[mt], bv[nt], o_acc[mt][nt], 0, 0, 0);
    }

    __syncthreads();
    if (kt < 31) {
      const int k0 = (kt + 1) * 64;
#pragma unroll
      for (int i = 0; i < 2; ++i) {
        int s = i * 256 + tid;
        int row = s >> 3;
        int c = (s & 7) ^ (row & 7);
        gl2lds16(kb + (((size_t)n * 2048 + k0 + row) << 10) + h * 64 + c * 8,
                 &Ks[s * 8]);
        gl2lds16(vtb + (((size_t)(h * 64 + row)) << 13) + (size_t)n * 2048 +
                     k0 + c * 8,
                 &Vts[s * 8]);
      }
    }
    __syncthreads();
  }

#pragma unroll
  for (int mt = 0; mt < 2; ++mt)
#pragma unroll
    for (int r = 0; r < 4; ++r) {
      float l = lrow[mt][r];
      l += __shfl_xor(l, 1);
      l += __shfl_xor(l, 2);
      l += __shfl_xor(l, 4);
      l += __shfl_xor(l, 8);
      float inv = 1.0f / l;
      int row_l = q0 + wave * 32 + mt * 16 + lg * 4 + r;
      size_t base = (((size_t)n * 2048 + row_l) << 10) + h * 64;
#pragma unroll
      for (int nt = 0; nt < 4; ++nt)
        aob[base + nt * 16 + lr] = f2bf(o_acc[mt][nt][r] * inv);
    }
}

// ---------------------------------------------------------------- launch
extern "C" void kernel_launch(void* const* d_in, const int* in_sizes, int n_in,
                              void* d_out, int out_size, void* d_ws,
                              size_t ws_size, hipStream_t stream) {
  const float* Q = (const float*)d_in[0];
  const float* K = (const float*)d_in[1];
  const float* V = (const float*)d_in[2];
  const float* Wq = (const float*)d_in[3];
  const float* bq = (const float*)d_in[4];
  const float* Wk = (const float*)d_in[5];
  const float* bk = (const float*)d_in[6];
  const float* Wv = (const float*)d_in[7];
  const float* bv = (const float*)d_in[8];
  const float* Wo = (const float*)d_in[9];
  const float* bo = (const float*)d_in[10];

  const size_t S = (size_t)8192 * 1024;
  const size_t W = (size_t)1024 * 1024;
  unsigned short* ws = (unsigned short*)d_ws;
  unsigned short* Qbf = ws;  // dead after q-proj; reused as attention output
  unsigned short* Kbf = ws + S;
  unsigned short* Vbf = ws + 2 * S;
  unsigned short* qbuf = ws + 3 * S;
  unsigned short* kbuf = ws + 4 * S;
  unsigned short* vtbuf = ws + 5 * S;
  unsigned short* Wqb = ws + 6 * S;
  unsigned short* Wkb = Wqb + W;
  unsigned short* Wvb = Wqb + 2 * W;
  unsigned short* Wob = Wqb + 3 * W;
  unsigned short* aob = Qbf;

  CvtArgs cx;
  cx.src[0] = Q; cx.dst[0] = Qbf;
  cx.src[1] = K; cx.dst[1] = Kbf;
  cx.src[2] = V; cx.dst[2] = Vbf;
  cx.src[3] = Q; cx.dst[3] = Qbf;  // unused slot
  cvt_multi_k<<<dim3(8192, 3), 256, 0, stream>>>(cx);

  CvtArgs cw;
  cw.src[0] = Wq; cw.dst[0] = Wqb;
  cw.src[1] = Wk; cw.dst[1] = Wkb;
  cw.src[2] = Wv; cw.dst[2] = Wvb;
  cw.src[3] = Wo; cw.dst[3] = Wob;
  cvt_multi_k<<<dim3(1024, 4), 256, 0, stream>>>(cw);

  // fused QKV projections: g0: q = (Qbf Wq^T + bq)*log2e/8  [8192x1024]
  //                        g1: k =  Kbf Wk^T + bk           [8192x1024]
  //                        g2: v^T = Wvb Vbf^T + bv (key-permuted) [1024x8192]
  GemmPack3 pp;
  pp.g[0] = {Qbf, Wqb, bq, qbuf, 1024, 3, LOG2E_OVER_SQRTD, 0, 0};
  pp.g[1] = {Kbf, Wkb, bk, kbuf, 1024, 3, 1.0f, 0, 0};
  pp.g[2] = {Wvb, Vbf, bv, vtbuf, 8192, 6, 1.0f, 1, 1};
  gemm_multi_k<false><<<1536, 256, 0, stream>>>(pp);

  attn_k<<<1024, 256, 0, stream>>>(qbuf, kbuf, vtbuf, aob);

  // out = AO Wo^T + bo  (fp32)
  GemmPack3 po;
  po.g[0] = {aob, Wob, bo, d_out, 1024, 3, 1.0f, 0, 0};
  po.g[1] = po.g[0];
  po.g[2] = po.g[0];
  gemm_multi_k<true><<<512, 256, 0, stream>>>(po);
}